// Round 6
// baseline (1248.443 us; speedup 1.0000x reference)
//
#include <hip/hip_runtime.h>
#include <math.h>

#define NB 4
#define NP 8192
#define KK 16
#define QPB 64
#define NPTS (NB * NP)

// ---- staged-filter geometry (round 6) ----
#define TSAMP 2048            // tau sample = candidates [0,2048)
#define TCH 256               // tau subchunk per wave
#define NTS 8                 // 8 waves per query-group (one group per block)
#define BCH 512               // filter chunk size
#define NBCH 16               // 16 chunks cover [0,8192)
#define CAP 14                // per-(query,chunk) index capacity
#define LSTRIDE 15            // u16 per (query,chunk): [0]=count, [1..14]=indices

// Fail-safe correctness (independent of tau's value):
//   S = {j : ref_d(j) <= tau}. tau = 16th-smallest over the first 2048, so
//   |S| >= 16 always and the exact top-16 is inside S; select's re-rank is
//   exact. Any chunk-count > CAP => exact full-scan fallback for that query.
//   Either way output equals the proven selection. tau bugs cost time only.

// comparator macros (exact: min/max introduce no rounding)
#define CSWAP_DESC(a, b) { float _lo = fminf(a, b); float _hi = fmaxf(a, b); a = _hi; b = _lo; }
#define CSWAP_ASC(a, b)  { float _lo = fminf(a, b); float _hi = fmaxf(a, b); a = _lo; b = _hi; }

// reference-rounded |p|^2 : (xx+yy)+zz
__device__ __forceinline__ float ref_sq(float x, float y, float z) {
  return __fadd_rn(__fadd_rn(__fmul_rn(x, x), __fmul_rn(y, y)), __fmul_rn(z, z));
}

// reference-rounded d2 = (sqq + sqc) - 2*dot, dot = (xx+yy)+zz
__device__ __forceinline__ float ref_d2q(float qx, float qy, float qz, float sqq,
                                         float4 c) {
  float dot = __fadd_rn(__fadd_rn(__fmul_rn(qx, c.x), __fmul_rn(qy, c.y)),
                        __fmul_rn(qz, c.z));
  float s = __fadd_rn(sqq, c.w);
  return __fmaf_rn(-2.0f, dot, s);
}

// batched top-16 update: 8 new distances d[0..7] vs sorted-asc bd[0..15]
__device__ __forceinline__ void topk_update(float bd[KK], float d[8]) {
  // Batcher odd-even mergesort-8, DESCENDING (19 comparators)
  CSWAP_DESC(d[0], d[1]) CSWAP_DESC(d[2], d[3]) CSWAP_DESC(d[4], d[5]) CSWAP_DESC(d[6], d[7])
  CSWAP_DESC(d[0], d[2]) CSWAP_DESC(d[1], d[3]) CSWAP_DESC(d[4], d[6]) CSWAP_DESC(d[5], d[7])
  CSWAP_DESC(d[1], d[2]) CSWAP_DESC(d[5], d[6])
  CSWAP_DESC(d[0], d[4]) CSWAP_DESC(d[1], d[5]) CSWAP_DESC(d[2], d[6]) CSWAP_DESC(d[3], d[7])
  CSWAP_DESC(d[2], d[4]) CSWAP_DESC(d[3], d[5])
  CSWAP_DESC(d[1], d[2]) CSWAP_DESC(d[3], d[4]) CSWAP_DESC(d[5], d[6])

  // [bd_asc(16), +inf x8, d_desc(8)] is bitonic; halver keeps 16 smallest
#pragma unroll
  for (int i = 0; i < 8; ++i) bd[8 + i] = fminf(bd[8 + i], d[i]);

  // bitonic merge-16 ascending cleanup (32 comparators)
#pragma unroll
  for (int i = 0; i < 8; ++i)  CSWAP_ASC(bd[i], bd[i + 8])
#pragma unroll
  for (int i = 0; i < 4; ++i)  CSWAP_ASC(bd[i], bd[i + 4])
#pragma unroll
  for (int i = 8; i < 12; ++i) CSWAP_ASC(bd[i], bd[i + 4])
#pragma unroll
  for (int g = 0; g < 4; ++g) {
    CSWAP_ASC(bd[4 * g + 0], bd[4 * g + 2]) CSWAP_ASC(bd[4 * g + 1], bd[4 * g + 3])
    CSWAP_ASC(bd[4 * g + 0], bd[4 * g + 1]) CSWAP_ASC(bd[4 * g + 2], bd[4 * g + 3])
  }
}

__global__ void prep_kernel(const float* __restrict__ x,
                            float4* __restrict__ cand) {
  int i = blockIdx.x * 256 + threadIdx.x;
  if (i < NPTS) {
    float px = x[3 * i + 0], py = x[3 * i + 1], pz = x[3 * i + 2];
    cand[i] = make_float4(px, py, pz, ref_sq(px, py, pz));
  }
}

// ---------------- kA: tau = 16th-smallest ref-dist over [0,2048) ------------
// One query-group per block; 8 subchunk-waves of 256 cands, LDS merge.
// 4096 waves total (R5: 2048). tau errors are harmless (fail-safe).
__global__ __launch_bounds__(512) void tau_stage_kernel(
    const float4* __restrict__ cand, float* __restrict__ tauArr) {
  __shared__ float s_t[NTS][64][KK];         // 32 KB
  const int tid   = threadIdx.x;
  const int lane  = tid & 63;
  const int w     = __builtin_amdgcn_readfirstlane(tid >> 6);
  const int sub   = w;                       // 0..7
  const int group = blockIdx.x;              // 0..511
  const int batch = group >> 7;
  const int qbase = (group & 127) * QPB;
  const float4* __restrict__ Cb = cand + (size_t)batch * NP;

  const float4 q = Cb[qbase + lane];
  const float qx = q.x, qy = q.y, qz = q.z, sqq = q.w;

  float bd[KK];
#pragma unroll
  for (int t = 0; t < KK; ++t) bd[t] = 3.4e38f;

  const int j0 = sub * TCH;
  for (int jj = 0; jj < TCH; jj += 8) {
    const float4* xp = Cb + (j0 + jj);       // wave-uniform address
    float4 c[8];
#pragma unroll
    for (int u = 0; u < 8; ++u) c[u] = xp[u];
    float d[8];
#pragma unroll
    for (int u = 0; u < 8; ++u) d[u] = ref_d2q(qx, qy, qz, sqq, c[u]);
    topk_update(bd, d);
  }

#pragma unroll
  for (int t = 0; t < KK; ++t) s_t[sub][lane][t] = bd[t];
  __syncthreads();

  if (w == 0) {                              // wave-uniform branch
    float md[KK];
#pragma unroll
    for (int t = 0; t < KK; ++t) md[t] = s_t[0][lane][t];  // sorted asc
#pragma unroll
    for (int s2 = 1; s2 < NTS; ++s2) {
      float d[KK];
#pragma unroll
      for (int t = 0; t < KK; ++t) d[t] = s_t[s2][lane][t];
      topk_update(md, &d[0]);
      topk_update(md, &d[8]);
    }
    tauArr[batch * NP + qbase + lane] = md[KK - 1];
  }
}

// ---------------- kB: threshold filter, 16 chunks of 512 -------------------
// wave-task gid = (group, chunk). Verbatim predicated-append body (proven).
// 8192 waves = 8/SIMD (R5: 4096 = 4/SIMD at VALUBusy 53%).
__global__ __launch_bounds__(512) void filter_kernel(
    const float4* __restrict__ cand, const float* __restrict__ tauArr,
    unsigned short* __restrict__ lists) {
  const int tid   = threadIdx.x;
  const int lane  = tid & 63;
  const int w     = __builtin_amdgcn_readfirstlane(tid >> 6);
  const int gid   = blockIdx.x * 8 + w;      // 0..8191
  const int group = gid >> 4;                // 0..511
  const int ch    = gid & 15;                // 0..15
  const int batch = group >> 7;
  const int qbase = (group & 127) * QPB;
  const int j0    = ch * BCH;
  const float4* __restrict__ Cb = cand + (size_t)batch * NP;

  const int qg = batch * NP + qbase + lane;
  const float tau = tauArr[qg];
  const float4 q = Cb[qbase + lane];
  const float qx = q.x, qy = q.y, qz = q.z, sqq = q.w;

  unsigned short* Lrow = lists + ((size_t)qg * NBCH + ch) * LSTRIDE;
  int cnt = 0;
  for (int jj = 0; jj < BCH; jj += 8) {
    const float4* xp = Cb + (j0 + jj);       // wave-uniform address
    float4 c[8];
#pragma unroll
    for (int u = 0; u < 8; ++u) c[u] = xp[u];
#pragma unroll
    for (int u = 0; u < 8; ++u) {
      float d = ref_d2q(qx, qy, qz, sqq, c[u]);
      if (d <= tau) {
        if (cnt < CAP) Lrow[1 + cnt] = (unsigned short)(j0 + jj + u);
        ++cnt;                               // count ALL survivors
      }
    }
  }
  Lrow[0] = (unsigned short)cnt;
}

// ---------------- kC: single-pass exact top-16 + covariance + eigen --------
// One query per thread, 64-thread blocks (512 blocks: all CUs covered).
// Survivor stream (ascending global index) -> proven insertion-with-index
// chain (fallback semantics: ties to earliest index, distance-sorted order).
__global__ __launch_bounds__(64) void select_eigen_kernel(
    const float4* __restrict__ cand, const unsigned short* __restrict__ lists,
    float* __restrict__ out) {
  const int tid = threadIdx.x;
  const int g = blockIdx.x * 64 + tid;       // global query id
  const int batch = g >> 13;                 // / NP
  const float4* __restrict__ Cb = cand + (size_t)batch * NP;
  const unsigned short* Lq = lists + (size_t)g * NBCH * LSTRIDE;

  const float4 qq = Cb[g & (NP - 1)];
  const float q2x = qq.x, q2y = qq.y, q2z = qq.z, sq2 = qq.w;

  int cns[NBCH];
  bool fs = false;
#pragma unroll
  for (int ch = 0; ch < NBCH; ++ch) {
    cns[ch] = (int)Lq[ch * LSTRIDE];
    if (cns[ch] > CAP) fs = true;            // overflow -> full scan
  }

  float md[KK]; int mjr[KK];
#pragma unroll
  for (int t = 0; t < KK; ++t) { md[t] = 3.4e38f; mjr[t] = 0; }

  if (!fs) {
    // single pass over survivors (ascending index), batched 8-wide gathers,
    // +inf pad (no-op for the d < md[15]-gated insertion chain).
    for (int ch = 0; ch < NBCH; ++ch) {
      const unsigned short* L = Lq + ch * LSTRIDE + 1;
      const int cn = cns[ch];
      for (int e = 0; e < cn; e += 8) {
        int jv[8];
        float dv[8];
#pragma unroll
        for (int u = 0; u < 8; ++u) {
          const bool ok = (e + u) < cn;
          jv[u] = ok ? (int)L[e + u] : 0;    // all 8 gathers in flight
          const float dd = ref_d2q(q2x, q2y, q2z, sq2, Cb[jv[u]]);
          dv[u] = ok ? dd : 3.4e38f;
        }
#pragma unroll
        for (int u = 0; u < 8; ++u) {
          const float d = dv[u];
          const int j = jv[u];
          if (d < md[KK - 1]) {
            bool c0 = d < md[0];
#pragma unroll
            for (int t = KK - 1; t >= 1; --t) {
              bool cl = d < md[t];
              bool cp = d < md[t - 1];
              float nv = fmaxf(md[t - 1], fminf(md[t], d));
              mjr[t] = cl ? (cp ? mjr[t - 1] : j) : mjr[t];
              md[t] = nv;
            }
            mjr[0] = c0 ? j : mjr[0];
            md[0] = fminf(md[0], d);
          }
        }
      }
    }
  } else {
    // exact full-scan insertion with index tracking (verbatim-proven)
    for (int j = 0; j < NP; ++j) {
      float d = ref_d2q(q2x, q2y, q2z, sq2, Cb[j]);
      if (d < md[KK - 1]) {
        bool c0 = d < md[0];
#pragma unroll
        for (int t = KK - 1; t >= 1; --t) {
          bool cl = d < md[t];
          bool cp = d < md[t - 1];
          float nv = fmaxf(md[t - 1], fminf(md[t], d));
          mjr[t] = cl ? (cp ? mjr[t - 1] : j) : mjr[t];
          md[t] = nv;
        }
        mjr[0] = c0 ? j : mjr[0];
        md[0] = fminf(md[0], d);
      }
    }
  }

  // ---- covariance + eigen tail (verbatim-verified arithmetic)
  float sx = 0.f, sy = 0.f, sz = 0.f;
#pragma unroll
  for (int s = 0; s < KK; ++s) {
    float4 pp = Cb[mjr[s]];
    sx = __fadd_rn(sx, pp.x);
    sy = __fadd_rn(sy, pp.y);
    sz = __fadd_rn(sz, pp.z);
  }
  const float k1 = 1.0f / KK;   // exact power of two
  const float mx = sx * k1, my = sy * k1, mz = sz * k1;

  float cxx = 0.f, cxy = 0.f, cxz = 0.f, cyy = 0.f, cyz = 0.f, czz = 0.f;
#pragma unroll
  for (int s = 0; s < KK; ++s) {
    float4 pp = Cb[mjr[s]];
    float dx = __fsub_rn(pp.x, mx);
    float dy = __fsub_rn(pp.y, my);
    float dz = __fsub_rn(pp.z, mz);
    cxx = __fadd_rn(cxx, __fmul_rn(dx, dx));
    cxy = __fadd_rn(cxy, __fmul_rn(dx, dy));
    cxz = __fadd_rn(cxz, __fmul_rn(dx, dz));
    cyy = __fadd_rn(cyy, __fmul_rn(dy, dy));
    cyz = __fadd_rn(cyz, __fmul_rn(dy, dz));
    czz = __fadd_rn(czz, __fmul_rn(dz, dz));
  }

  double a   = (double)__fmul_rn(cxx, k1), b = (double)__fmul_rn(cyy, k1);
  double c2  = (double)__fmul_rn(czz, k1);
  double dxy = (double)__fmul_rn(cxy, k1), exz = (double)__fmul_rn(cxz, k1);
  double fyz = (double)__fmul_rn(cyz, k1);
  double qm = (a + b + c2) / 3.0;
  double p1 = dxy * dxy + exz * exz + fyz * fyz;
  double aa = a - qm, bb = b - qm, cc = c2 - qm;
  double p2 = aa * aa + bb * bb + cc * cc + 2.0 * p1;
  double ratio;
  if (p2 <= 0.0) {
    ratio = 1.0;
  } else {
    double p  = sqrt(p2 / 6.0);
    double ip = 1.0 / p;
    double b00 = aa * ip, b11 = bb * ip, b22 = cc * ip;
    double b01 = dxy * ip, b02 = exz * ip, b12 = fyz * ip;
    double detB = b00 * (b11 * b22 - b12 * b12)
                - b01 * (b01 * b22 - b12 * b02)
                + b02 * (b01 * b12 - b11 * b02);
    double r = 0.5 * detB;
    r = fmin(1.0, fmax(-1.0, r));
    double phi = acos(r) / 3.0;
    double e0 = qm + 2.0 * p * cos(phi);                      // largest
    double e2 = qm + 2.0 * p * cos(phi + 2.0943951023931954); // smallest
    double e1 = 3.0 * qm - e0 - e2;                           // middle
    ratio = e0 / e1;
  }
  out[g] = (float)ratio;
}

// ---------------- fallback: verbatim single kernel (proven pass) ------------
__global__ __launch_bounds__(512, 4) void knn_eigen_fallback(
    const float4* __restrict__ cand, float* __restrict__ out) {
  __shared__ unsigned short s_j[8][QPB][18];

  const int tid   = threadIdx.x;
  const int lane  = tid & 63;
  const int w     = __builtin_amdgcn_readfirstlane(tid >> 6);
  const int batch = blockIdx.x >> 7;
  const int qbase = (blockIdx.x & 127) * QPB;
  const int FCH   = NP / 8;   // 1024

  const float4* __restrict__ Cb = cand + (size_t)batch * NP;

  const float4 q = Cb[qbase + lane];
  const float qx = q.x, qy = q.y, qz = q.z, sqq = q.w;

  float bd[KK];
#pragma unroll
  for (int t = 0; t < KK; ++t) bd[t] = 3.4e38f;

  const int j0 = w * FCH;
  for (int jj = 0; jj < FCH; jj += 8) {
    const float4* xp = Cb + (j0 + jj);
    float4 c[8];
#pragma unroll
    for (int u = 0; u < 8; ++u) c[u] = xp[u];
    float d[8];
#pragma unroll
    for (int u = 0; u < 8; ++u) d[u] = ref_d2q(qx, qy, qz, sqq, c[u]);
    topk_update(bd, d);
  }

  const float T = bd[KK - 1];
  int cnt = 0;
  for (int jj = 0; jj < FCH; jj += 8) {
    const float4* xp = Cb + (j0 + jj);
    float4 c[8];
#pragma unroll
    for (int u = 0; u < 8; ++u) c[u] = xp[u];
#pragma unroll
    for (int u = 0; u < 8; ++u) {
      float d = ref_d2q(qx, qy, qz, sqq, c[u]);
      if (d <= T && cnt < KK) {
        s_j[w][lane][cnt] = (unsigned short)(j0 + jj + u);
        cnt++;
      }
    }
  }
  __syncthreads();

  if (tid < QPB) {
    const float4 qq = Cb[qbase + tid];
    const float q2x = qq.x, q2y = qq.y, q2z = qq.z, sq2 = qq.w;
    float md[KK]; int mj[KK];
#pragma unroll
    for (int t = 0; t < KK; ++t) { md[t] = 3.4e38f; mj[t] = 0; }
    for (int cch = 0; cch < 8; ++cch) {
      const unsigned int* rowp = (const unsigned int*)&s_j[cch][tid][0];
#pragma unroll
      for (int sp = 0; sp < KK / 2; ++sp) {
        unsigned int pk = rowp[sp];
#pragma unroll
        for (int half = 0; half < 2; ++half) {
          int j = (half == 0) ? (int)(pk & 0xFFFFu) : (int)(pk >> 16);
          float d = ref_d2q(q2x, q2y, q2z, sq2, Cb[j]);
          if (d < md[KK - 1]) {
            bool c0 = d < md[0];
#pragma unroll
            for (int t = KK - 1; t >= 1; --t) {
              bool cl = d < md[t];
              bool cp = d < md[t - 1];
              float nv = fmaxf(md[t - 1], fminf(md[t], d));
              mj[t] = cl ? (cp ? mj[t - 1] : j) : mj[t];
              md[t] = nv;
            }
            mj[0] = c0 ? j : mj[0];
            md[0] = fminf(md[0], d);
          }
        }
      }
    }
    float sx = 0.f, sy = 0.f, sz = 0.f;
#pragma unroll
    for (int s = 0; s < KK; ++s) {
      float4 pp = Cb[mj[s]];
      sx = __fadd_rn(sx, pp.x);
      sy = __fadd_rn(sy, pp.y);
      sz = __fadd_rn(sz, pp.z);
    }
    const float k1 = 1.0f / KK;
    const float mx = sx * k1, my = sy * k1, mz = sz * k1;
    float cxx = 0.f, cxy = 0.f, cxz = 0.f, cyy = 0.f, cyz = 0.f, czz = 0.f;
#pragma unroll
    for (int s = 0; s < KK; ++s) {
      float4 pp = Cb[mj[s]];
      float dx = __fsub_rn(pp.x, mx);
      float dy = __fsub_rn(pp.y, my);
      float dz = __fsub_rn(pp.z, mz);
      cxx = __fadd_rn(cxx, __fmul_rn(dx, dx));
      cxy = __fadd_rn(cxy, __fmul_rn(dx, dy));
      cxz = __fadd_rn(cxz, __fmul_rn(dx, dz));
      cyy = __fadd_rn(cyy, __fmul_rn(dy, dy));
      cyz = __fadd_rn(cyz, __fmul_rn(dy, dz));
      czz = __fadd_rn(czz, __fmul_rn(dz, dz));
    }
    double a   = (double)__fmul_rn(cxx, k1), b = (double)__fmul_rn(cyy, k1);
    double c2  = (double)__fmul_rn(czz, k1);
    double dxy = (double)__fmul_rn(cxy, k1), exz = (double)__fmul_rn(cxz, k1);
    double fyz = (double)__fmul_rn(cyz, k1);
    double qm = (a + b + c2) / 3.0;
    double p1 = dxy * dxy + exz * exz + fyz * fyz;
    double aa = a - qm, bb = b - qm, cc = c2 - qm;
    double p2 = aa * aa + bb * bb + cc * cc + 2.0 * p1;
    double ratio;
    if (p2 <= 0.0) {
      ratio = 1.0;
    } else {
      double p  = sqrt(p2 / 6.0);
      double ip = 1.0 / p;
      double b00 = aa * ip, b11 = bb * ip, b22 = cc * ip;
      double b01 = dxy * ip, b02 = exz * ip, b12 = fyz * ip;
      double detB = b00 * (b11 * b22 - b12 * b12)
                  - b01 * (b01 * b22 - b12 * b02)
                  + b02 * (b01 * b12 - b11 * b02);
      double r = 0.5 * detB;
      r = fmin(1.0, fmax(-1.0, r));
      double phi = acos(r) / 3.0;
      double e0 = qm + 2.0 * p * cos(phi);
      double e2 = qm + 2.0 * p * cos(phi + 2.0943951023931954);
      double e1 = 3.0 * qm - e0 - e2;
      ratio = e0 / e1;
    }
    out[(size_t)batch * NP + qbase + tid] = (float)ratio;
  }
}

extern "C" void kernel_launch(void* const* d_in, const int* in_sizes, int n_in,
                              void* d_out, int out_size, void* d_ws, size_t ws_size,
                              hipStream_t stream) {
  const float* x = (const float*)d_in[0];
  float* out = (float*)d_out;
  float4* cand = (float4*)d_ws;                                   // 512 KB
  float* tauArr = (float*)((char*)d_ws + (size_t)NPTS * sizeof(float4)); // 128 KB
  unsigned short* lists =
      (unsigned short*)((char*)d_ws + (size_t)NPTS * sizeof(float4) +
                        (size_t)NPTS * sizeof(float));            // ~15.73 MB
  const size_t need = (size_t)NPTS * sizeof(float4) +
                      (size_t)NPTS * sizeof(float) +
                      (size_t)NPTS * NBCH * LSTRIDE * sizeof(unsigned short);
  // need = 16,384,000 B < proven-available 17,301,504 B

  prep_kernel<<<dim3(NPTS / 256), dim3(256), 0, stream>>>(x, cand);
  if (ws_size >= need) {
    tau_stage_kernel<<<dim3(512), dim3(512), 0, stream>>>(cand, tauArr);
    filter_kernel<<<dim3(1024), dim3(512), 0, stream>>>(cand, tauArr, lists);
    select_eigen_kernel<<<dim3(NPTS / 64), dim3(64), 0, stream>>>(cand, lists, out);
  } else {
    knn_eigen_fallback<<<dim3(NPTS / QPB), dim3(512), 0, stream>>>(cand, out);
  }
}

// Round 7
// 288.056 us; speedup vs baseline: 4.3340x; 4.3340x over previous
//
#include <hip/hip_runtime.h>
#include <math.h>

#define NB 4
#define NP 8192
#define KK 16
#define QPB 64
#define NPTS (NB * NP)

// ---- staged-filter geometry (round 7) ----
#define TSAMP 2048            // tau sample = candidates [0,2048)
#define TCH 256               // tau subchunk per wave
#define NTS 8                 // 8 waves per query-group (one group per block)
#define BCH 1024              // filter chunk size   (R5 proven: zero overflow)
#define NBCH 8                // 8 chunks cover [0,8192)
#define CAP 30                // per-(query,chunk) index capacity
#define LSTRIDE 31            // u16 per (query,chunk): [0]=count, [1..30]=indices

// Fail-safe correctness (independent of tau's value):
//   S = {j : ref_d(j) <= tau}. tau = 16th-smallest over the first 2048, so
//   |S| >= 16 always and the exact top-16 is inside S. Any chunk-count > CAP
//   => exact full-scan fallback for that query (R6 lesson: this path costs
//   ~700us per affected wave, so CAP must make it statistically dead --
//   CAP=30 @ 1024-chunks: P(overflow) ~ 1e-10, zero observed in R4/R5).

// comparator macros (exact: min/max introduce no rounding)
#define CSWAP_DESC(a, b) { float _lo = fminf(a, b); float _hi = fmaxf(a, b); a = _hi; b = _lo; }
#define CSWAP_ASC(a, b)  { float _lo = fminf(a, b); float _hi = fmaxf(a, b); a = _lo; b = _hi; }

// reference-rounded |p|^2 : (xx+yy)+zz
__device__ __forceinline__ float ref_sq(float x, float y, float z) {
  return __fadd_rn(__fadd_rn(__fmul_rn(x, x), __fmul_rn(y, y)), __fmul_rn(z, z));
}

// reference-rounded d2 = (sqq + sqc) - 2*dot, dot = (xx+yy)+zz
__device__ __forceinline__ float ref_d2q(float qx, float qy, float qz, float sqq,
                                         float4 c) {
  float dot = __fadd_rn(__fadd_rn(__fmul_rn(qx, c.x), __fmul_rn(qy, c.y)),
                        __fmul_rn(qz, c.z));
  float s = __fadd_rn(sqq, c.w);
  return __fmaf_rn(-2.0f, dot, s);
}

// batched top-16 update: 8 new distances d[0..7] vs sorted-asc bd[0..15]
__device__ __forceinline__ void topk_update(float bd[KK], float d[8]) {
  // Batcher odd-even mergesort-8, DESCENDING (19 comparators)
  CSWAP_DESC(d[0], d[1]) CSWAP_DESC(d[2], d[3]) CSWAP_DESC(d[4], d[5]) CSWAP_DESC(d[6], d[7])
  CSWAP_DESC(d[0], d[2]) CSWAP_DESC(d[1], d[3]) CSWAP_DESC(d[4], d[6]) CSWAP_DESC(d[5], d[7])
  CSWAP_DESC(d[1], d[2]) CSWAP_DESC(d[5], d[6])
  CSWAP_DESC(d[0], d[4]) CSWAP_DESC(d[1], d[5]) CSWAP_DESC(d[2], d[6]) CSWAP_DESC(d[3], d[7])
  CSWAP_DESC(d[2], d[4]) CSWAP_DESC(d[3], d[5])
  CSWAP_DESC(d[1], d[2]) CSWAP_DESC(d[3], d[4]) CSWAP_DESC(d[5], d[6])

  // [bd_asc(16), +inf x8, d_desc(8)] is bitonic; halver keeps 16 smallest
#pragma unroll
  for (int i = 0; i < 8; ++i) bd[8 + i] = fminf(bd[8 + i], d[i]);

  // bitonic merge-16 ascending cleanup (32 comparators)
#pragma unroll
  for (int i = 0; i < 8; ++i)  CSWAP_ASC(bd[i], bd[i + 8])
#pragma unroll
  for (int i = 0; i < 4; ++i)  CSWAP_ASC(bd[i], bd[i + 4])
#pragma unroll
  for (int i = 8; i < 12; ++i) CSWAP_ASC(bd[i], bd[i + 4])
#pragma unroll
  for (int g = 0; g < 4; ++g) {
    CSWAP_ASC(bd[4 * g + 0], bd[4 * g + 2]) CSWAP_ASC(bd[4 * g + 1], bd[4 * g + 3])
    CSWAP_ASC(bd[4 * g + 0], bd[4 * g + 1]) CSWAP_ASC(bd[4 * g + 2], bd[4 * g + 3])
  }
}

__global__ void prep_kernel(const float* __restrict__ x,
                            float4* __restrict__ cand) {
  int i = blockIdx.x * 256 + threadIdx.x;
  if (i < NPTS) {
    float px = x[3 * i + 0], py = x[3 * i + 1], pz = x[3 * i + 2];
    cand[i] = make_float4(px, py, pz, ref_sq(px, py, pz));
  }
}

// ---------------- kA: tau = 16th-smallest ref-dist over [0,2048) ------------
// One query-group per block; 8 subchunk-waves of 256 cands, LDS merge.
// tau errors are harmless (fail-safe) -- this stage only affects speed.
__global__ __launch_bounds__(512) void tau_stage_kernel(
    const float4* __restrict__ cand, float* __restrict__ tauArr) {
  __shared__ float s_t[NTS][64][KK];         // 32 KB
  const int tid   = threadIdx.x;
  const int lane  = tid & 63;
  const int w     = __builtin_amdgcn_readfirstlane(tid >> 6);
  const int sub   = w;                       // 0..7
  const int group = blockIdx.x;              // 0..511
  const int batch = group >> 7;
  const int qbase = (group & 127) * QPB;
  const float4* __restrict__ Cb = cand + (size_t)batch * NP;

  const float4 q = Cb[qbase + lane];
  const float qx = q.x, qy = q.y, qz = q.z, sqq = q.w;

  float bd[KK];
#pragma unroll
  for (int t = 0; t < KK; ++t) bd[t] = 3.4e38f;

  const int j0 = sub * TCH;
  for (int jj = 0; jj < TCH; jj += 8) {
    const float4* xp = Cb + (j0 + jj);       // wave-uniform address
    float4 c[8];
#pragma unroll
    for (int u = 0; u < 8; ++u) c[u] = xp[u];
    float d[8];
#pragma unroll
    for (int u = 0; u < 8; ++u) d[u] = ref_d2q(qx, qy, qz, sqq, c[u]);
    topk_update(bd, d);
  }

#pragma unroll
  for (int t = 0; t < KK; ++t) s_t[sub][lane][t] = bd[t];
  __syncthreads();

  if (w == 0) {                              // wave-uniform branch
    float md[KK];
#pragma unroll
    for (int t = 0; t < KK; ++t) md[t] = s_t[0][lane][t];  // sorted asc
#pragma unroll
    for (int s2 = 1; s2 < NTS; ++s2) {
      float d[KK];
#pragma unroll
      for (int t = 0; t < KK; ++t) d[t] = s_t[s2][lane][t];
      topk_update(md, &d[0]);
      topk_update(md, &d[8]);
    }
    tauArr[batch * NP + qbase + lane] = md[KK - 1];
  }
}

// ---------------- kB: threshold filter, 8 chunks of 1024 -------------------
// wave-task = (group, chunk). Verbatim predicated-append semantics; loads
// batched 16-wide for ILP (R5 showed VALUBusy 53% = latency-stalled).
__global__ __launch_bounds__(512) void filter_kernel(
    const float4* __restrict__ cand, const float* __restrict__ tauArr,
    unsigned short* __restrict__ lists) {
  const int tid   = threadIdx.x;
  const int lane  = tid & 63;
  const int w     = __builtin_amdgcn_readfirstlane(tid >> 6);
  const int group = blockIdx.x;              // 0..511
  const int batch = group >> 7;
  const int qbase = (group & 127) * QPB;
  const int ch    = w;                       // 0..7
  const int j0    = ch * BCH;
  const float4* __restrict__ Cb = cand + (size_t)batch * NP;

  const int qg = batch * NP + qbase + lane;
  const float tau = tauArr[qg];
  const float4 q = Cb[qbase + lane];
  const float qx = q.x, qy = q.y, qz = q.z, sqq = q.w;

  unsigned short* Lrow = lists + ((size_t)qg * NBCH + ch) * LSTRIDE;
  int cnt = 0;
  for (int jj = 0; jj < BCH; jj += 16) {
    const float4* xp = Cb + (j0 + jj);       // wave-uniform address
    float4 c[16];
#pragma unroll
    for (int u = 0; u < 16; ++u) c[u] = xp[u];   // 16 loads in flight
#pragma unroll
    for (int u = 0; u < 16; ++u) {
      float d = ref_d2q(qx, qy, qz, sqq, c[u]);
      if (d <= tau) {
        if (cnt < CAP) Lrow[1 + cnt] = (unsigned short)(j0 + jj + u);
        ++cnt;                               // count ALL survivors
      }
    }
  }
  Lrow[0] = (unsigned short)cnt;
}

// ---------------- kC: single-pass exact top-16 + covariance + eigen --------
// One query per thread, 64-thread blocks (512 blocks: all CUs covered).
// Survivor stream (ascending global index) -> proven insertion-with-index
// chain. Distance-sorted neighbor order == lax.top_k gather order
// (R6 measured absmax 0.0).
__global__ __launch_bounds__(64) void select_eigen_kernel(
    const float4* __restrict__ cand, const unsigned short* __restrict__ lists,
    float* __restrict__ out) {
  const int tid = threadIdx.x;
  const int g = blockIdx.x * 64 + tid;       // global query id
  const int batch = g >> 13;                 // / NP
  const float4* __restrict__ Cb = cand + (size_t)batch * NP;
  const unsigned short* Lq = lists + (size_t)g * NBCH * LSTRIDE;

  const float4 qq = Cb[g & (NP - 1)];
  const float q2x = qq.x, q2y = qq.y, q2z = qq.z, sq2 = qq.w;

  int cns[NBCH];
  bool fs = false;
#pragma unroll
  for (int ch = 0; ch < NBCH; ++ch) {
    cns[ch] = (int)Lq[ch * LSTRIDE];
    if (cns[ch] > CAP) fs = true;            // overflow -> full scan
  }

  float md[KK]; int mjr[KK];
#pragma unroll
  for (int t = 0; t < KK; ++t) { md[t] = 3.4e38f; mjr[t] = 0; }

  if (!fs) {
    // single pass over survivors (ascending index), batched 8-wide gathers,
    // +inf pad (no-op for the d < md[15]-gated insertion chain).
    for (int ch = 0; ch < NBCH; ++ch) {
      const unsigned short* L = Lq + ch * LSTRIDE + 1;
      const int cn = cns[ch];
      for (int e = 0; e < cn; e += 8) {
        int jv[8];
        float dv[8];
#pragma unroll
        for (int u = 0; u < 8; ++u) {
          const bool ok = (e + u) < cn;
          jv[u] = ok ? (int)L[e + u] : 0;    // all 8 gathers in flight
          const float dd = ref_d2q(q2x, q2y, q2z, sq2, Cb[jv[u]]);
          dv[u] = ok ? dd : 3.4e38f;
        }
#pragma unroll
        for (int u = 0; u < 8; ++u) {
          const float d = dv[u];
          const int j = jv[u];
          if (d < md[KK - 1]) {
            bool c0 = d < md[0];
#pragma unroll
            for (int t = KK - 1; t >= 1; --t) {
              bool cl = d < md[t];
              bool cp = d < md[t - 1];
              float nv = fmaxf(md[t - 1], fminf(md[t], d));
              mjr[t] = cl ? (cp ? mjr[t - 1] : j) : mjr[t];
              md[t] = nv;
            }
            mjr[0] = c0 ? j : mjr[0];
            md[0] = fminf(md[0], d);
          }
        }
      }
    }
  } else {
    // exact full-scan insertion with index tracking (verbatim-proven)
    for (int j = 0; j < NP; ++j) {
      float d = ref_d2q(q2x, q2y, q2z, sq2, Cb[j]);
      if (d < md[KK - 1]) {
        bool c0 = d < md[0];
#pragma unroll
        for (int t = KK - 1; t >= 1; --t) {
          bool cl = d < md[t];
          bool cp = d < md[t - 1];
          float nv = fmaxf(md[t - 1], fminf(md[t], d));
          mjr[t] = cl ? (cp ? mjr[t - 1] : j) : mjr[t];
          md[t] = nv;
        }
        mjr[0] = c0 ? j : mjr[0];
        md[0] = fminf(md[0], d);
      }
    }
  }

  // ---- covariance + eigen tail (verbatim-verified arithmetic)
  float sx = 0.f, sy = 0.f, sz = 0.f;
#pragma unroll
  for (int s = 0; s < KK; ++s) {
    float4 pp = Cb[mjr[s]];
    sx = __fadd_rn(sx, pp.x);
    sy = __fadd_rn(sy, pp.y);
    sz = __fadd_rn(sz, pp.z);
  }
  const float k1 = 1.0f / KK;   // exact power of two
  const float mx = sx * k1, my = sy * k1, mz = sz * k1;

  float cxx = 0.f, cxy = 0.f, cxz = 0.f, cyy = 0.f, cyz = 0.f, czz = 0.f;
#pragma unroll
  for (int s = 0; s < KK; ++s) {
    float4 pp = Cb[mjr[s]];
    float dx = __fsub_rn(pp.x, mx);
    float dy = __fsub_rn(pp.y, my);
    float dz = __fsub_rn(pp.z, mz);
    cxx = __fadd_rn(cxx, __fmul_rn(dx, dx));
    cxy = __fadd_rn(cxy, __fmul_rn(dx, dy));
    cxz = __fadd_rn(cxz, __fmul_rn(dx, dz));
    cyy = __fadd_rn(cyy, __fmul_rn(dy, dy));
    cyz = __fadd_rn(cyz, __fmul_rn(dy, dz));
    czz = __fadd_rn(czz, __fmul_rn(dz, dz));
  }

  double a   = (double)__fmul_rn(cxx, k1), b = (double)__fmul_rn(cyy, k1);
  double c2  = (double)__fmul_rn(czz, k1);
  double dxy = (double)__fmul_rn(cxy, k1), exz = (double)__fmul_rn(cxz, k1);
  double fyz = (double)__fmul_rn(cyz, k1);
  double qm = (a + b + c2) / 3.0;
  double p1 = dxy * dxy + exz * exz + fyz * fyz;
  double aa = a - qm, bb = b - qm, cc = c2 - qm;
  double p2 = aa * aa + bb * bb + cc * cc + 2.0 * p1;
  double ratio;
  if (p2 <= 0.0) {
    ratio = 1.0;
  } else {
    double p  = sqrt(p2 / 6.0);
    double ip = 1.0 / p;
    double b00 = aa * ip, b11 = bb * ip, b22 = cc * ip;
    double b01 = dxy * ip, b02 = exz * ip, b12 = fyz * ip;
    double detB = b00 * (b11 * b22 - b12 * b12)
                - b01 * (b01 * b22 - b12 * b02)
                + b02 * (b01 * b12 - b11 * b02);
    double r = 0.5 * detB;
    r = fmin(1.0, fmax(-1.0, r));
    double phi = acos(r) / 3.0;
    double e0 = qm + 2.0 * p * cos(phi);                      // largest
    double e2 = qm + 2.0 * p * cos(phi + 2.0943951023931954); // smallest
    double e1 = 3.0 * qm - e0 - e2;                           // middle
    ratio = e0 / e1;
  }
  out[g] = (float)ratio;
}

// ---------------- fallback: verbatim single kernel (proven pass) ------------
__global__ __launch_bounds__(512, 4) void knn_eigen_fallback(
    const float4* __restrict__ cand, float* __restrict__ out) {
  __shared__ unsigned short s_j[8][QPB][18];

  const int tid   = threadIdx.x;
  const int lane  = tid & 63;
  const int w     = __builtin_amdgcn_readfirstlane(tid >> 6);
  const int batch = blockIdx.x >> 7;
  const int qbase = (blockIdx.x & 127) * QPB;
  const int FCH   = NP / 8;   // 1024

  const float4* __restrict__ Cb = cand + (size_t)batch * NP;

  const float4 q = Cb[qbase + lane];
  const float qx = q.x, qy = q.y, qz = q.z, sqq = q.w;

  float bd[KK];
#pragma unroll
  for (int t = 0; t < KK; ++t) bd[t] = 3.4e38f;

  const int j0 = w * FCH;
  for (int jj = 0; jj < FCH; jj += 8) {
    const float4* xp = Cb + (j0 + jj);
    float4 c[8];
#pragma unroll
    for (int u = 0; u < 8; ++u) c[u] = xp[u];
    float d[8];
#pragma unroll
    for (int u = 0; u < 8; ++u) d[u] = ref_d2q(qx, qy, qz, sqq, c[u]);
    topk_update(bd, d);
  }

  const float T = bd[KK - 1];
  int cnt = 0;
  for (int jj = 0; jj < FCH; jj += 8) {
    const float4* xp = Cb + (j0 + jj);
    float4 c[8];
#pragma unroll
    for (int u = 0; u < 8; ++u) c[u] = xp[u];
#pragma unroll
    for (int u = 0; u < 8; ++u) {
      float d = ref_d2q(qx, qy, qz, sqq, c[u]);
      if (d <= T && cnt < KK) {
        s_j[w][lane][cnt] = (unsigned short)(j0 + jj + u);
        cnt++;
      }
    }
  }
  __syncthreads();

  if (tid < QPB) {
    const float4 qq = Cb[qbase + tid];
    const float q2x = qq.x, q2y = qq.y, q2z = qq.z, sq2 = qq.w;
    float md[KK]; int mj[KK];
#pragma unroll
    for (int t = 0; t < KK; ++t) { md[t] = 3.4e38f; mj[t] = 0; }
    for (int cch = 0; cch < 8; ++cch) {
      const unsigned int* rowp = (const unsigned int*)&s_j[cch][tid][0];
#pragma unroll
      for (int sp = 0; sp < KK / 2; ++sp) {
        unsigned int pk = rowp[sp];
#pragma unroll
        for (int half = 0; half < 2; ++half) {
          int j = (half == 0) ? (int)(pk & 0xFFFFu) : (int)(pk >> 16);
          float d = ref_d2q(q2x, q2y, q2z, sq2, Cb[j]);
          if (d < md[KK - 1]) {
            bool c0 = d < md[0];
#pragma unroll
            for (int t = KK - 1; t >= 1; --t) {
              bool cl = d < md[t];
              bool cp = d < md[t - 1];
              float nv = fmaxf(md[t - 1], fminf(md[t], d));
              mj[t] = cl ? (cp ? mj[t - 1] : j) : mj[t];
              md[t] = nv;
            }
            mj[0] = c0 ? j : mj[0];
            md[0] = fminf(md[0], d);
          }
        }
      }
    }
    float sx = 0.f, sy = 0.f, sz = 0.f;
#pragma unroll
    for (int s = 0; s < KK; ++s) {
      float4 pp = Cb[mj[s]];
      sx = __fadd_rn(sx, pp.x);
      sy = __fadd_rn(sy, pp.y);
      sz = __fadd_rn(sz, pp.z);
    }
    const float k1 = 1.0f / KK;
    const float mx = sx * k1, my = sy * k1, mz = sz * k1;
    float cxx = 0.f, cxy = 0.f, cxz = 0.f, cyy = 0.f, cyz = 0.f, czz = 0.f;
#pragma unroll
    for (int s = 0; s < KK; ++s) {
      float4 pp = Cb[mj[s]];
      float dx = __fsub_rn(pp.x, mx);
      float dy = __fsub_rn(pp.y, my);
      float dz = __fsub_rn(pp.z, mz);
      cxx = __fadd_rn(cxx, __fmul_rn(dx, dx));
      cxy = __fadd_rn(cxy, __fmul_rn(dx, dy));
      cxz = __fadd_rn(cxz, __fmul_rn(dx, dz));
      cyy = __fadd_rn(cyy, __fmul_rn(dy, dy));
      cyz = __fadd_rn(cyz, __fmul_rn(dy, dz));
      czz = __fadd_rn(czz, __fmul_rn(dz, dz));
    }
    double a   = (double)__fmul_rn(cxx, k1), b = (double)__fmul_rn(cyy, k1);
    double c2  = (double)__fmul_rn(czz, k1);
    double dxy = (double)__fmul_rn(cxy, k1), exz = (double)__fmul_rn(cxz, k1);
    double fyz = (double)__fmul_rn(cyz, k1);
    double qm = (a + b + c2) / 3.0;
    double p1 = dxy * dxy + exz * exz + fyz * fyz;
    double aa = a - qm, bb = b - qm, cc = c2 - qm;
    double p2 = aa * aa + bb * bb + cc * cc + 2.0 * p1;
    double ratio;
    if (p2 <= 0.0) {
      ratio = 1.0;
    } else {
      double p  = sqrt(p2 / 6.0);
      double ip = 1.0 / p;
      double b00 = aa * ip, b11 = bb * ip, b22 = cc * ip;
      double b01 = dxy * ip, b02 = exz * ip, b12 = fyz * ip;
      double detB = b00 * (b11 * b22 - b12 * b12)
                  - b01 * (b01 * b22 - b12 * b02)
                  + b02 * (b01 * b12 - b11 * b02);
      double r = 0.5 * detB;
      r = fmin(1.0, fmax(-1.0, r));
      double phi = acos(r) / 3.0;
      double e0 = qm + 2.0 * p * cos(phi);
      double e2 = qm + 2.0 * p * cos(phi + 2.0943951023931954);
      double e1 = 3.0 * qm - e0 - e2;
      ratio = e0 / e1;
    }
    out[(size_t)batch * NP + qbase + tid] = (float)ratio;
  }
}

extern "C" void kernel_launch(void* const* d_in, const int* in_sizes, int n_in,
                              void* d_out, int out_size, void* d_ws, size_t ws_size,
                              hipStream_t stream) {
  const float* x = (const float*)d_in[0];
  float* out = (float*)d_out;
  float4* cand = (float4*)d_ws;                                   // 512 KB
  float* tauArr = (float*)((char*)d_ws + (size_t)NPTS * sizeof(float4)); // 128 KB
  unsigned short* lists =
      (unsigned short*)((char*)d_ws + (size_t)NPTS * sizeof(float4) +
                        (size_t)NPTS * sizeof(float));            // ~16.25 MB
  const size_t need = (size_t)NPTS * sizeof(float4) +
                      (size_t)NPTS * sizeof(float) +
                      (size_t)NPTS * NBCH * LSTRIDE * sizeof(unsigned short);
  // need = 16,908,288 B < proven-available 17,301,504 B

  prep_kernel<<<dim3(NPTS / 256), dim3(256), 0, stream>>>(x, cand);
  if (ws_size >= need) {
    tau_stage_kernel<<<dim3(512), dim3(512), 0, stream>>>(cand, tauArr);
    filter_kernel<<<dim3(512), dim3(512), 0, stream>>>(cand, tauArr, lists);
    select_eigen_kernel<<<dim3(NPTS / 64), dim3(64), 0, stream>>>(cand, lists, out);
  } else {
    knn_eigen_fallback<<<dim3(NPTS / QPB), dim3(512), 0, stream>>>(cand, out);
  }
}

// Round 8
// 257.800 us; speedup vs baseline: 4.8427x; 1.1174x over previous
//
#include <hip/hip_runtime.h>
#include <math.h>

#define NB 4
#define NP 8192
#define KK 16
#define QPB 64
#define NPTS (NB * NP)

// ---- staged-filter geometry (round 8) ----
#define TSAMP 2048            // tau sample = candidates [0,2048)
#define TCH 256               // tau subchunk per wave
#define NTS 8                 // tau: 8 waves per query-group
#define BCH 1024              // filter chunk size   (R5/R7 proven: zero overflow)
#define NBCH 8                // 8 chunks cover [0,8192)
#define CAP 30                // per-(query,chunk) capacity (proven geometry)
#define SROW 34               // u16 per (chunk,query) LDS row: [0]=cnt,[1..30]=idx (+pad)
#define SCH (64 * SROW + 2)   // LDS chunk stride in u16 (=2178; %32 words == 1: no bank conflict)
#define RECW 248              // u16 per query record (496 B)
#define RECCAP 240            // max survivors stored per query
// record layout: [0]=total cnt (0xFFFF = overflow flag), [1..7] pad,
//                [8..8+239] survivor indices, ascending global index.
// Fail-safe: tau = exact ref 16th-smallest of first 2048 => >=16 survivors,
// top-16 subset of survivors. Flagged record => exact full-scan. Selection
// stream order identical to R7 (absmax 0.0 proven).

// comparator macros (exact: min/max introduce no rounding)
#define CSWAP_DESC(a, b) { float _lo = fminf(a, b); float _hi = fmaxf(a, b); a = _hi; b = _lo; }
#define CSWAP_ASC(a, b)  { float _lo = fminf(a, b); float _hi = fmaxf(a, b); a = _lo; b = _hi; }

// reference-rounded |p|^2 : (xx+yy)+zz
__device__ __forceinline__ float ref_sq(float x, float y, float z) {
  return __fadd_rn(__fadd_rn(__fmul_rn(x, x), __fmul_rn(y, y)), __fmul_rn(z, z));
}

// reference-rounded d2 = (sqq + sqc) - 2*dot, dot = (xx+yy)+zz
__device__ __forceinline__ float ref_d2q(float qx, float qy, float qz, float sqq,
                                         float4 c) {
  float dot = __fadd_rn(__fadd_rn(__fmul_rn(qx, c.x), __fmul_rn(qy, c.y)),
                        __fmul_rn(qz, c.z));
  float s = __fadd_rn(sqq, c.w);
  return __fmaf_rn(-2.0f, dot, s);
}

// batched top-16 update: 8 new distances d[0..7] vs sorted-asc bd[0..15]
__device__ __forceinline__ void topk_update(float bd[KK], float d[8]) {
  CSWAP_DESC(d[0], d[1]) CSWAP_DESC(d[2], d[3]) CSWAP_DESC(d[4], d[5]) CSWAP_DESC(d[6], d[7])
  CSWAP_DESC(d[0], d[2]) CSWAP_DESC(d[1], d[3]) CSWAP_DESC(d[4], d[6]) CSWAP_DESC(d[5], d[7])
  CSWAP_DESC(d[1], d[2]) CSWAP_DESC(d[5], d[6])
  CSWAP_DESC(d[0], d[4]) CSWAP_DESC(d[1], d[5]) CSWAP_DESC(d[2], d[6]) CSWAP_DESC(d[3], d[7])
  CSWAP_DESC(d[2], d[4]) CSWAP_DESC(d[3], d[5])
  CSWAP_DESC(d[1], d[2]) CSWAP_DESC(d[3], d[4]) CSWAP_DESC(d[5], d[6])
#pragma unroll
  for (int i = 0; i < 8; ++i) bd[8 + i] = fminf(bd[8 + i], d[i]);
#pragma unroll
  for (int i = 0; i < 8; ++i)  CSWAP_ASC(bd[i], bd[i + 8])
#pragma unroll
  for (int i = 0; i < 4; ++i)  CSWAP_ASC(bd[i], bd[i + 4])
#pragma unroll
  for (int i = 8; i < 12; ++i) CSWAP_ASC(bd[i], bd[i + 4])
#pragma unroll
  for (int g = 0; g < 4; ++g) {
    CSWAP_ASC(bd[4 * g + 0], bd[4 * g + 2]) CSWAP_ASC(bd[4 * g + 1], bd[4 * g + 3])
    CSWAP_ASC(bd[4 * g + 0], bd[4 * g + 1]) CSWAP_ASC(bd[4 * g + 2], bd[4 * g + 3])
  }
}

__global__ void prep_kernel(const float* __restrict__ x,
                            float4* __restrict__ cand) {
  int i = blockIdx.x * 256 + threadIdx.x;
  if (i < NPTS) {
    float px = x[3 * i + 0], py = x[3 * i + 1], pz = x[3 * i + 2];
    cand[i] = make_float4(px, py, pz, ref_sq(px, py, pz));
  }
}

// ---------------- kA: tau = 16th-smallest ref-dist over [0,2048) ------------
// (verbatim R7: one group per block, 8 subchunk-waves, LDS merge)
__global__ __launch_bounds__(512) void tau_stage_kernel(
    const float4* __restrict__ cand, float* __restrict__ tauArr) {
  __shared__ float s_t[NTS][64][KK + 1];     // +1 pad breaks bank conflicts
  const int tid   = threadIdx.x;
  const int lane  = tid & 63;
  const int w     = __builtin_amdgcn_readfirstlane(tid >> 6);
  const int sub   = w;                       // 0..7
  const int group = blockIdx.x;              // 0..511
  const int batch = group >> 7;
  const int qbase = (group & 127) * QPB;
  const float4* __restrict__ Cb = cand + (size_t)batch * NP;

  const float4 q = Cb[qbase + lane];
  const float qx = q.x, qy = q.y, qz = q.z, sqq = q.w;

  float bd[KK];
#pragma unroll
  for (int t = 0; t < KK; ++t) bd[t] = 3.4e38f;

  const int j0 = sub * TCH;
  for (int jj = 0; jj < TCH; jj += 8) {
    const float4* xp = Cb + (j0 + jj);       // wave-uniform address
    float4 c[8];
#pragma unroll
    for (int u = 0; u < 8; ++u) c[u] = xp[u];
    float d[8];
#pragma unroll
    for (int u = 0; u < 8; ++u) d[u] = ref_d2q(qx, qy, qz, sqq, c[u]);
    topk_update(bd, d);
  }

#pragma unroll
  for (int t = 0; t < KK; ++t) s_t[sub][lane][t] = bd[t];
  __syncthreads();

  if (w == 0) {                              // wave-uniform branch
    float md[KK];
#pragma unroll
    for (int t = 0; t < KK; ++t) md[t] = s_t[0][lane][t];
#pragma unroll
    for (int s2 = 1; s2 < NTS; ++s2) {
      float d[KK];
#pragma unroll
      for (int t = 0; t < KK; ++t) d[t] = s_t[s2][lane][t];
      topk_update(md, &d[0]);
      topk_update(md, &d[8]);
    }
    tauArr[batch * NP + qbase + lane] = md[KK - 1];
  }
}

// ---------------- kB: threshold filter -> LDS -> compact global record ------
// Block = query-group (64 queries), 8 waves, wave w scans chunk w (proven
// body). Then 8 threads/query compact LDS rows into one contiguous 496B
// record (chunk asc, entry asc == R7's consumed stream order).
__global__ __launch_bounds__(512) void filter_kernel(
    const float4* __restrict__ cand, const float* __restrict__ tauArr,
    unsigned short* __restrict__ rec) {
  __shared__ unsigned short s_idx[NBCH * SCH];   // 34,848 B
  const int tid   = threadIdx.x;
  const int lane  = tid & 63;
  const int w     = __builtin_amdgcn_readfirstlane(tid >> 6);
  const int group = blockIdx.x;              // 0..511
  const int batch = group >> 7;
  const int qbase = (group & 127) * QPB;
  const int j0    = w * BCH;
  const float4* __restrict__ Cb = cand + (size_t)batch * NP;

  const int qg = batch * NP + qbase + lane;
  const float tau = tauArr[qg];
  const float4 q = Cb[qbase + lane];
  const float qx = q.x, qy = q.y, qz = q.z, sqq = q.w;

  unsigned short* Srow = &s_idx[w * SCH + lane * SROW];
  int cnt = 0;
  for (int jj = 0; jj < BCH; jj += 16) {
    const float4* xp = Cb + (j0 + jj);       // wave-uniform address
    float4 c[16];
#pragma unroll
    for (int u = 0; u < 16; ++u) c[u] = xp[u];   // 16 loads in flight
#pragma unroll
    for (int u = 0; u < 16; ++u) {
      float d = ref_d2q(qx, qy, qz, sqq, c[u]);
      if (d <= tau) {
        if (cnt < CAP) Srow[1 + cnt] = (unsigned short)(j0 + jj + u);
        ++cnt;                               // count ALL survivors
      }
    }
  }
  Srow[0] = (unsigned short)cnt;
  __syncthreads();

  // compaction: 8 threads per query (ql = tid>>3, p = tid&7 = source chunk)
  const int ql = tid >> 3;
  const int p  = tid & 7;
  int off = 0, myc = 0, total = 0, mx = 0;
#pragma unroll
  for (int c = 0; c < NBCH; ++c) {
    const int cc  = (int)s_idx[c * SCH + ql * SROW];
    const int ccw = cc < CAP ? cc : CAP;
    if (c < p) off += ccw;
    if (c == p) myc = ccw;
    total += cc;
    mx = cc > mx ? cc : mx;
  }
  const int qg2 = batch * NP + qbase + ql;
  unsigned short* R = rec + (size_t)qg2 * RECW;
  if (p == 0)
    R[0] = (unsigned short)((mx > CAP || total > RECCAP) ? 0xFFFFu
                                                         : (unsigned)total);
  const unsigned short* Ssrc = &s_idx[p * SCH + ql * SROW + 1];
  for (int e = 0; e < myc; ++e) {
    const int dst = off + e;
    if (dst < RECCAP) R[8 + dst] = Ssrc[e];
  }
}

// ---------------- kC: single-pass exact top-16 + covariance + eigen --------
// One query per thread. Record is contiguous: header + aligned int4 batches
// of 8 survivors, all loads in flight. Chain/covariance/eigen verbatim R7
// (absmax 0.0 proven). Flagged or short record => exact full-scan.
__global__ __launch_bounds__(64) void select_eigen_kernel(
    const float4* __restrict__ cand, const unsigned short* __restrict__ rec,
    float* __restrict__ out) {
  const int tid = threadIdx.x;
  const int g = blockIdx.x * 64 + tid;       // global query id
  const int batch = g >> 13;                 // / NP
  const float4* __restrict__ Cb = cand + (size_t)batch * NP;
  const unsigned short* R = rec + (size_t)g * RECW;

  const float4 qq = Cb[g & (NP - 1)];
  const float q2x = qq.x, q2y = qq.y, q2z = qq.z, sq2 = qq.w;

  const int cntw = (int)R[0];
  bool fs = (cntw == 0xFFFF) || (cntw < KK);
  const int cnt = fs ? 0 : cntw;

  float md[KK]; int mjr[KK];
#pragma unroll
  for (int t = 0; t < KK; ++t) { md[t] = 3.4e38f; mjr[t] = 0; }

  if (!fs) {
    const unsigned short* L = R + 8;         // 16B-aligned survivor stream
    for (int e = 0; e < cnt; e += 8) {
      const int4 raw = *(const int4*)(L + e);   // one dwordx4: 8 indices
      int jv[8];
      jv[0] = raw.x & 0xFFFF;  jv[1] = (raw.x >> 16) & 0xFFFF;
      jv[2] = raw.y & 0xFFFF;  jv[3] = (raw.y >> 16) & 0xFFFF;
      jv[4] = raw.z & 0xFFFF;  jv[5] = (raw.z >> 16) & 0xFFFF;
      jv[6] = raw.w & 0xFFFF;  jv[7] = (raw.w >> 16) & 0xFFFF;
      float dv[8];
#pragma unroll
      for (int u = 0; u < 8; ++u) {
        const bool ok = (e + u) < cnt;
        const int j = ok ? jv[u] : 0;
        jv[u] = j;
        const float dd = ref_d2q(q2x, q2y, q2z, sq2, Cb[j]);  // 8 in flight
        dv[u] = ok ? dd : 3.4e38f;           // +inf pad: chain no-op
      }
#pragma unroll
      for (int u = 0; u < 8; ++u) {
        const float d = dv[u];
        const int j = jv[u];
        if (d < md[KK - 1]) {
          bool c0 = d < md[0];
#pragma unroll
          for (int t = KK - 1; t >= 1; --t) {
            bool cl = d < md[t];
            bool cp = d < md[t - 1];
            float nv = fmaxf(md[t - 1], fminf(md[t], d));
            mjr[t] = cl ? (cp ? mjr[t - 1] : j) : mjr[t];
            md[t] = nv;
          }
          mjr[0] = c0 ? j : mjr[0];
          md[0] = fminf(md[0], d);
        }
      }
    }
  } else {
    // exact full-scan insertion with index tracking (verbatim-proven)
    for (int j = 0; j < NP; ++j) {
      float d = ref_d2q(q2x, q2y, q2z, sq2, Cb[j]);
      if (d < md[KK - 1]) {
        bool c0 = d < md[0];
#pragma unroll
        for (int t = KK - 1; t >= 1; --t) {
          bool cl = d < md[t];
          bool cp = d < md[t - 1];
          float nv = fmaxf(md[t - 1], fminf(md[t], d));
          mjr[t] = cl ? (cp ? mjr[t - 1] : j) : mjr[t];
          md[t] = nv;
        }
        mjr[0] = c0 ? j : mjr[0];
        md[0] = fminf(md[0], d);
      }
    }
  }

  // ---- covariance + eigen tail (verbatim-verified arithmetic)
  float sx = 0.f, sy = 0.f, sz = 0.f;
#pragma unroll
  for (int s = 0; s < KK; ++s) {
    float4 pp = Cb[mjr[s]];
    sx = __fadd_rn(sx, pp.x);
    sy = __fadd_rn(sy, pp.y);
    sz = __fadd_rn(sz, pp.z);
  }
  const float k1 = 1.0f / KK;   // exact power of two
  const float mx = sx * k1, my = sy * k1, mz = sz * k1;

  float cxx = 0.f, cxy = 0.f, cxz = 0.f, cyy = 0.f, cyz = 0.f, czz = 0.f;
#pragma unroll
  for (int s = 0; s < KK; ++s) {
    float4 pp = Cb[mjr[s]];
    float dx = __fsub_rn(pp.x, mx);
    float dy = __fsub_rn(pp.y, my);
    float dz = __fsub_rn(pp.z, mz);
    cxx = __fadd_rn(cxx, __fmul_rn(dx, dx));
    cxy = __fadd_rn(cxy, __fmul_rn(dx, dy));
    cxz = __fadd_rn(cxz, __fmul_rn(dx, dz));
    cyy = __fadd_rn(cyy, __fmul_rn(dy, dy));
    cyz = __fadd_rn(cyz, __fmul_rn(dy, dz));
    czz = __fadd_rn(czz, __fmul_rn(dz, dz));
  }

  double a   = (double)__fmul_rn(cxx, k1), b = (double)__fmul_rn(cyy, k1);
  double c2  = (double)__fmul_rn(czz, k1);
  double dxy = (double)__fmul_rn(cxy, k1), exz = (double)__fmul_rn(cxz, k1);
  double fyz = (double)__fmul_rn(cyz, k1);
  double qm = (a + b + c2) / 3.0;
  double p1 = dxy * dxy + exz * exz + fyz * fyz;
  double aa = a - qm, bb = b - qm, cc = c2 - qm;
  double p2 = aa * aa + bb * bb + cc * cc + 2.0 * p1;
  double ratio;
  if (p2 <= 0.0) {
    ratio = 1.0;
  } else {
    double p  = sqrt(p2 / 6.0);
    double ip = 1.0 / p;
    double b00 = aa * ip, b11 = bb * ip, b22 = cc * ip;
    double b01 = dxy * ip, b02 = exz * ip, b12 = fyz * ip;
    double detB = b00 * (b11 * b22 - b12 * b12)
                - b01 * (b01 * b22 - b12 * b02)
                + b02 * (b01 * b12 - b11 * b02);
    double r = 0.5 * detB;
    r = fmin(1.0, fmax(-1.0, r));
    double phi = acos(r) / 3.0;
    double e0 = qm + 2.0 * p * cos(phi);                      // largest
    double e2 = qm + 2.0 * p * cos(phi + 2.0943951023931954); // smallest
    double e1 = 3.0 * qm - e0 - e2;                           // middle
    ratio = e0 / e1;
  }
  out[g] = (float)ratio;
}

// ---------------- fallback: verbatim single kernel (proven pass) ------------
__global__ __launch_bounds__(512, 4) void knn_eigen_fallback(
    const float4* __restrict__ cand, float* __restrict__ out) {
  __shared__ unsigned short s_j[8][QPB][18];

  const int tid   = threadIdx.x;
  const int lane  = tid & 63;
  const int w     = __builtin_amdgcn_readfirstlane(tid >> 6);
  const int batch = blockIdx.x >> 7;
  const int qbase = (blockIdx.x & 127) * QPB;
  const int FCH   = NP / 8;   // 1024

  const float4* __restrict__ Cb = cand + (size_t)batch * NP;

  const float4 q = Cb[qbase + lane];
  const float qx = q.x, qy = q.y, qz = q.z, sqq = q.w;

  float bd[KK];
#pragma unroll
  for (int t = 0; t < KK; ++t) bd[t] = 3.4e38f;

  const int j0 = w * FCH;
  for (int jj = 0; jj < FCH; jj += 8) {
    const float4* xp = Cb + (j0 + jj);
    float4 c[8];
#pragma unroll
    for (int u = 0; u < 8; ++u) c[u] = xp[u];
    float d[8];
#pragma unroll
    for (int u = 0; u < 8; ++u) d[u] = ref_d2q(qx, qy, qz, sqq, c[u]);
    topk_update(bd, d);
  }

  const float T = bd[KK - 1];
  int cnt = 0;
  for (int jj = 0; jj < FCH; jj += 8) {
    const float4* xp = Cb + (j0 + jj);
    float4 c[8];
#pragma unroll
    for (int u = 0; u < 8; ++u) c[u] = xp[u];
#pragma unroll
    for (int u = 0; u < 8; ++u) {
      float d = ref_d2q(qx, qy, qz, sqq, c[u]);
      if (d <= T && cnt < KK) {
        s_j[w][lane][cnt] = (unsigned short)(j0 + jj + u);
        cnt++;
      }
    }
  }
  __syncthreads();

  if (tid < QPB) {
    const float4 qq = Cb[qbase + tid];
    const float q2x = qq.x, q2y = qq.y, q2z = qq.z, sq2 = qq.w;
    float md[KK]; int mj[KK];
#pragma unroll
    for (int t = 0; t < KK; ++t) { md[t] = 3.4e38f; mj[t] = 0; }
    for (int cch = 0; cch < 8; ++cch) {
      const unsigned int* rowp = (const unsigned int*)&s_j[cch][tid][0];
#pragma unroll
      for (int sp = 0; sp < KK / 2; ++sp) {
        unsigned int pk = rowp[sp];
#pragma unroll
        for (int half = 0; half < 2; ++half) {
          int j = (half == 0) ? (int)(pk & 0xFFFFu) : (int)(pk >> 16);
          float d = ref_d2q(q2x, q2y, q2z, sq2, Cb[j]);
          if (d < md[KK - 1]) {
            bool c0 = d < md[0];
#pragma unroll
            for (int t = KK - 1; t >= 1; --t) {
              bool cl = d < md[t];
              bool cp = d < md[t - 1];
              float nv = fmaxf(md[t - 1], fminf(md[t], d));
              mj[t] = cl ? (cp ? mj[t - 1] : j) : mj[t];
              md[t] = nv;
            }
            mj[0] = c0 ? j : mj[0];
            md[0] = fminf(md[0], d);
          }
        }
      }
    }
    float sx = 0.f, sy = 0.f, sz = 0.f;
#pragma unroll
    for (int s = 0; s < KK; ++s) {
      float4 pp = Cb[mj[s]];
      sx = __fadd_rn(sx, pp.x);
      sy = __fadd_rn(sy, pp.y);
      sz = __fadd_rn(sz, pp.z);
    }
    const float k1 = 1.0f / KK;
    const float mx = sx * k1, my = sy * k1, mz = sz * k1;
    float cxx = 0.f, cxy = 0.f, cxz = 0.f, cyy = 0.f, cyz = 0.f, czz = 0.f;
#pragma unroll
    for (int s = 0; s < KK; ++s) {
      float4 pp = Cb[mj[s]];
      float dx = __fsub_rn(pp.x, mx);
      float dy = __fsub_rn(pp.y, my);
      float dz = __fsub_rn(pp.z, mz);
      cxx = __fadd_rn(cxx, __fmul_rn(dx, dx));
      cxy = __fadd_rn(cxy, __fmul_rn(dx, dy));
      cxz = __fadd_rn(cxz, __fmul_rn(dx, dz));
      cyy = __fadd_rn(cyy, __fmul_rn(dy, dy));
      cyz = __fadd_rn(cyz, __fmul_rn(dy, dz));
      czz = __fadd_rn(czz, __fmul_rn(dz, dz));
    }
    double a   = (double)__fmul_rn(cxx, k1), b = (double)__fmul_rn(cyy, k1);
    double c2  = (double)__fmul_rn(czz, k1);
    double dxy = (double)__fmul_rn(cxy, k1), exz = (double)__fmul_rn(cxz, k1);
    double fyz = (double)__fmul_rn(cyz, k1);
    double qm = (a + b + c2) / 3.0;
    double p1 = dxy * dxy + exz * exz + fyz * fyz;
    double aa = a - qm, bb = b - qm, cc = c2 - qm;
    double p2 = aa * aa + bb * bb + cc * cc + 2.0 * p1;
    double ratio;
    if (p2 <= 0.0) {
      ratio = 1.0;
    } else {
      double p  = sqrt(p2 / 6.0);
      double ip = 1.0 / p;
      double b00 = aa * ip, b11 = bb * ip, b22 = cc * ip;
      double b01 = dxy * ip, b02 = exz * ip, b12 = fyz * ip;
      double detB = b00 * (b11 * b22 - b12 * b12)
                  - b01 * (b01 * b22 - b12 * b02)
                  + b02 * (b01 * b12 - b11 * b02);
      double r = 0.5 * detB;
      r = fmin(1.0, fmax(-1.0, r));
      double phi = acos(r) / 3.0;
      double e0 = qm + 2.0 * p * cos(phi);
      double e2 = qm + 2.0 * p * cos(phi + 2.0943951023931954);
      double e1 = 3.0 * qm - e0 - e2;
      ratio = e0 / e1;
    }
    out[(size_t)batch * NP + qbase + tid] = (float)ratio;
  }
}

extern "C" void kernel_launch(void* const* d_in, const int* in_sizes, int n_in,
                              void* d_out, int out_size, void* d_ws, size_t ws_size,
                              hipStream_t stream) {
  const float* x = (const float*)d_in[0];
  float* out = (float*)d_out;
  float4* cand = (float4*)d_ws;                                   // 512 KB
  float* tauArr = (float*)((char*)d_ws + (size_t)NPTS * sizeof(float4)); // 128 KB
  unsigned short* rec =
      (unsigned short*)((char*)d_ws + (size_t)NPTS * sizeof(float4) +
                        (size_t)NPTS * sizeof(float));            // 15.5 MB
  const size_t need = (size_t)NPTS * sizeof(float4) +
                      (size_t)NPTS * sizeof(float) +
                      (size_t)NPTS * RECW * sizeof(unsigned short);
  // need = 16,908,288 B == R7's proven budget

  prep_kernel<<<dim3(NPTS / 256), dim3(256), 0, stream>>>(x, cand);
  if (ws_size >= need) {
    tau_stage_kernel<<<dim3(512), dim3(512), 0, stream>>>(cand, tauArr);
    filter_kernel<<<dim3(512), dim3(512), 0, stream>>>(cand, tauArr, rec);
    select_eigen_kernel<<<dim3(NPTS / 64), dim3(64), 0, stream>>>(cand, rec, out);
  } else {
    knn_eigen_fallback<<<dim3(NPTS / QPB), dim3(512), 0, stream>>>(cand, out);
  }
}

// Round 9
// 253.495 us; speedup vs baseline: 4.9249x; 1.0170x over previous
//
#include <hip/hip_runtime.h>
#include <math.h>

#define NB 4
#define NP 8192
#define KK 16
#define QPB 64
#define NPTS (NB * NP)

// ---- staged-filter geometry (round 9) ----
#define TSAMP 2048            // tau sample = candidates [0,2048)
#define TCH 256               // tau subchunk per wave
#define NTS 8                 // tau: 8 waves per query-group
#define BCH 1024              // filter chunk size   (R5/R7/R8 proven: zero overflow)
#define NBCH 8                // 8 chunks cover [0,8192)
#define CAP 30                // per-(query,chunk) capacity (proven geometry)
#define SROW 34               // u16 per (chunk,query) LDS row: [0]=cnt,[1..30]=idx (+pad)
#define SCH (64 * SROW + 2)   // LDS chunk stride in u16 (=2178)
#define RECW 248              // u16 per query record (496 B)
#define RECCAP 240            // max survivors stored per query
// record layout: [0]=total cnt (0xFFFF = overflow flag), [1..7] pad,
//                [8..8+239] survivor indices, ascending global index.
// Fail-safe: tau = exact ref 16th-smallest of first 2048 => >=16 survivors,
// top-16 subset of survivors. Flagged record => exact full-scan. Selection
// stream order identical to R8 (absmax 0.0 proven).

// comparator macros (exact: min/max introduce no rounding)
#define CSWAP_DESC(a, b) { float _lo = fminf(a, b); float _hi = fmaxf(a, b); a = _hi; b = _lo; }
#define CSWAP_ASC(a, b)  { float _lo = fminf(a, b); float _hi = fmaxf(a, b); a = _lo; b = _hi; }

// reference-rounded |p|^2 : (xx+yy)+zz
__device__ __forceinline__ float ref_sq(float x, float y, float z) {
  return __fadd_rn(__fadd_rn(__fmul_rn(x, x), __fmul_rn(y, y)), __fmul_rn(z, z));
}

// reference-rounded d2 = (sqq + sqc) - 2*dot, dot = (xx+yy)+zz
__device__ __forceinline__ float ref_d2q(float qx, float qy, float qz, float sqq,
                                         float4 c) {
  float dot = __fadd_rn(__fadd_rn(__fmul_rn(qx, c.x), __fmul_rn(qy, c.y)),
                        __fmul_rn(qz, c.z));
  float s = __fadd_rn(sqq, c.w);
  return __fmaf_rn(-2.0f, dot, s);
}

// batched top-16 update: 8 new distances d[0..7] vs sorted-asc bd[0..15]
__device__ __forceinline__ void topk_update(float bd[KK], float d[8]) {
  CSWAP_DESC(d[0], d[1]) CSWAP_DESC(d[2], d[3]) CSWAP_DESC(d[4], d[5]) CSWAP_DESC(d[6], d[7])
  CSWAP_DESC(d[0], d[2]) CSWAP_DESC(d[1], d[3]) CSWAP_DESC(d[4], d[6]) CSWAP_DESC(d[5], d[7])
  CSWAP_DESC(d[1], d[2]) CSWAP_DESC(d[5], d[6])
  CSWAP_DESC(d[0], d[4]) CSWAP_DESC(d[1], d[5]) CSWAP_DESC(d[2], d[6]) CSWAP_DESC(d[3], d[7])
  CSWAP_DESC(d[2], d[4]) CSWAP_DESC(d[3], d[5])
  CSWAP_DESC(d[1], d[2]) CSWAP_DESC(d[3], d[4]) CSWAP_DESC(d[5], d[6])
#pragma unroll
  for (int i = 0; i < 8; ++i) bd[8 + i] = fminf(bd[8 + i], d[i]);
#pragma unroll
  for (int i = 0; i < 8; ++i)  CSWAP_ASC(bd[i], bd[i + 8])
#pragma unroll
  for (int i = 0; i < 4; ++i)  CSWAP_ASC(bd[i], bd[i + 4])
#pragma unroll
  for (int i = 8; i < 12; ++i) CSWAP_ASC(bd[i], bd[i + 4])
#pragma unroll
  for (int g = 0; g < 4; ++g) {
    CSWAP_ASC(bd[4 * g + 0], bd[4 * g + 2]) CSWAP_ASC(bd[4 * g + 1], bd[4 * g + 3])
    CSWAP_ASC(bd[4 * g + 0], bd[4 * g + 1]) CSWAP_ASC(bd[4 * g + 2], bd[4 * g + 3])
  }
}

__global__ void prep_kernel(const float* __restrict__ x,
                            float4* __restrict__ cand) {
  int i = blockIdx.x * 256 + threadIdx.x;
  if (i < NPTS) {
    float px = x[3 * i + 0], py = x[3 * i + 1], pz = x[3 * i + 2];
    cand[i] = make_float4(px, py, pz, ref_sq(px, py, pz));
  }
}

// ---------------- kA: tau = 16th-smallest ref-dist over [0,2048) ------------
// Round 9: sample staged into LDS once per block (coalesced vector loads);
// scan reads LDS with uniform addresses (broadcast, conflict-free). R8's
// uniform GLOBAL loads were scalarized (VGPR=24/SGPR=96) into s_load +
// lgkmcnt(0) drains per batch -> ~85us latency-bound. Merge-list region
// overlays the sample region after a barrier (34.8KB total).
// tau errors are harmless (fail-safe) -- this stage only affects speed.
__global__ __launch_bounds__(512) void tau_stage_kernel(
    const float4* __restrict__ cand, float* __restrict__ tauArr) {
  __shared__ __align__(16) char smem[NTS * 64 * 17 * 4];   // 34,816 B
  float4* samp = (float4*)smem;                            // [2048] phases 1-2
  float (*s_t)[64][17] = (float (*)[64][17])smem;          // [8][64][17] 3-4
  const int tid   = threadIdx.x;
  const int lane  = tid & 63;
  const int w     = __builtin_amdgcn_readfirstlane(tid >> 6);
  const int group = blockIdx.x;              // 0..511
  const int batch = group >> 7;
  const int qbase = (group & 127) * QPB;
  const float4* __restrict__ Cb = cand + (size_t)batch * NP;

  const float4 q = Cb[qbase + lane];
  const float qx = q.x, qy = q.y, qz = q.z, sqq = q.w;

  // phase 1: cooperative stage of sample [0,2048) -- coalesced dwordx4
#pragma unroll
  for (int r = 0; r < TSAMP / 512; ++r)
    samp[r * 512 + tid] = Cb[r * 512 + tid];
  __syncthreads();

  // phase 2: scan own subchunk from LDS (verbatim body; LDS source)
  float bd[KK];
#pragma unroll
  for (int t = 0; t < KK; ++t) bd[t] = 3.4e38f;

  const int j0 = w * TCH;
  for (int jj = 0; jj < TCH; jj += 8) {
    const float4* xp = samp + (j0 + jj);     // uniform LDS addr: broadcast
    float4 c[8];
#pragma unroll
    for (int u = 0; u < 8; ++u) c[u] = xp[u];
    float d[8];
#pragma unroll
    for (int u = 0; u < 8; ++u) d[u] = ref_d2q(qx, qy, qz, sqq, c[u]);
    topk_update(bd, d);
  }
  __syncthreads();                           // everyone done reading samp

  // phase 3: publish sorted sub-lists (overlays samp region)
#pragma unroll
  for (int t = 0; t < KK; ++t) s_t[w][lane][t] = bd[t];
  __syncthreads();

  // phase 4: wave 0 merges (verbatim)
  if (w == 0) {
    float md[KK];
#pragma unroll
    for (int t = 0; t < KK; ++t) md[t] = s_t[0][lane][t];
#pragma unroll
    for (int s2 = 1; s2 < NTS; ++s2) {
      float d[KK];
#pragma unroll
      for (int t = 0; t < KK; ++t) d[t] = s_t[s2][lane][t];
      topk_update(md, &d[0]);
      topk_update(md, &d[8]);
    }
    tauArr[batch * NP + qbase + lane] = md[KK - 1];
  }
}

// ---------------- kB: threshold filter -> LDS -> compact global record ------
// VERBATIM R8 (measured 87.2us anchor).
__global__ __launch_bounds__(512) void filter_kernel(
    const float4* __restrict__ cand, const float* __restrict__ tauArr,
    unsigned short* __restrict__ rec) {
  __shared__ unsigned short s_idx[NBCH * SCH];   // 34,848 B
  const int tid   = threadIdx.x;
  const int lane  = tid & 63;
  const int w     = __builtin_amdgcn_readfirstlane(tid >> 6);
  const int group = blockIdx.x;              // 0..511
  const int batch = group >> 7;
  const int qbase = (group & 127) * QPB;
  const int j0    = w * BCH;
  const float4* __restrict__ Cb = cand + (size_t)batch * NP;

  const int qg = batch * NP + qbase + lane;
  const float tau = tauArr[qg];
  const float4 q = Cb[qbase + lane];
  const float qx = q.x, qy = q.y, qz = q.z, sqq = q.w;

  unsigned short* Srow = &s_idx[w * SCH + lane * SROW];
  int cnt = 0;
  for (int jj = 0; jj < BCH; jj += 16) {
    const float4* xp = Cb + (j0 + jj);       // wave-uniform address
    float4 c[16];
#pragma unroll
    for (int u = 0; u < 16; ++u) c[u] = xp[u];   // 16 loads in flight
#pragma unroll
    for (int u = 0; u < 16; ++u) {
      float d = ref_d2q(qx, qy, qz, sqq, c[u]);
      if (d <= tau) {
        if (cnt < CAP) Srow[1 + cnt] = (unsigned short)(j0 + jj + u);
        ++cnt;                               // count ALL survivors
      }
    }
  }
  Srow[0] = (unsigned short)cnt;
  __syncthreads();

  // compaction: 8 threads per query (ql = tid>>3, p = tid&7 = source chunk)
  const int ql = tid >> 3;
  const int p  = tid & 7;
  int off = 0, myc = 0, total = 0, mx = 0;
#pragma unroll
  for (int c = 0; c < NBCH; ++c) {
    const int cc  = (int)s_idx[c * SCH + ql * SROW];
    const int ccw = cc < CAP ? cc : CAP;
    if (c < p) off += ccw;
    if (c == p) myc = ccw;
    total += cc;
    mx = cc > mx ? cc : mx;
  }
  const int qg2 = batch * NP + qbase + ql;
  unsigned short* R = rec + (size_t)qg2 * RECW;
  if (p == 0)
    R[0] = (unsigned short)((mx > CAP || total > RECCAP) ? 0xFFFFu
                                                         : (unsigned)total);
  const unsigned short* Ssrc = &s_idx[p * SCH + ql * SROW + 1];
  for (int e = 0; e < myc; ++e) {
    const int dst = off + e;
    if (dst < RECCAP) R[8 + dst] = Ssrc[e];
  }
}

// ---------------- kC: single-pass exact top-16 + covariance + eigen --------
// Round 9: 16-wide super-batches (2 int4 index loads + 16 gathers in flight)
// and selected points cached in registers for the tail (bitwise-identical
// values). Chain semantics/stream order verbatim (absmax 0.0 proven).
__global__ __launch_bounds__(64) void select_eigen_kernel(
    const float4* __restrict__ cand, const unsigned short* __restrict__ rec,
    float* __restrict__ out) {
  const int tid = threadIdx.x;
  const int g = blockIdx.x * 64 + tid;       // global query id
  const int batch = g >> 13;                 // / NP
  const float4* __restrict__ Cb = cand + (size_t)batch * NP;
  const unsigned short* R = rec + (size_t)g * RECW;

  const float4 qq = Cb[g & (NP - 1)];
  const float q2x = qq.x, q2y = qq.y, q2z = qq.z, sq2 = qq.w;

  const int cntw = (int)R[0];
  bool fs = (cntw == 0xFFFF) || (cntw < KK);
  const int cnt = fs ? 0 : cntw;

  float md[KK]; int mjr[KK];
#pragma unroll
  for (int t = 0; t < KK; ++t) { md[t] = 3.4e38f; mjr[t] = 0; }

  if (!fs) {
    const unsigned short* L = R + 8;         // 16B-aligned survivor stream
    for (int e = 0; e < cnt; e += 16) {
      const int4 raw0 = *(const int4*)(L + e);      // dwordx4: 8 indices
      const int4 raw1 = *(const int4*)(L + e + 8);  // dwordx4: 8 more
      int jv[16];
      jv[0]  = raw0.x & 0xFFFF;  jv[1]  = (raw0.x >> 16) & 0xFFFF;
      jv[2]  = raw0.y & 0xFFFF;  jv[3]  = (raw0.y >> 16) & 0xFFFF;
      jv[4]  = raw0.z & 0xFFFF;  jv[5]  = (raw0.z >> 16) & 0xFFFF;
      jv[6]  = raw0.w & 0xFFFF;  jv[7]  = (raw0.w >> 16) & 0xFFFF;
      jv[8]  = raw1.x & 0xFFFF;  jv[9]  = (raw1.x >> 16) & 0xFFFF;
      jv[10] = raw1.y & 0xFFFF;  jv[11] = (raw1.y >> 16) & 0xFFFF;
      jv[12] = raw1.z & 0xFFFF;  jv[13] = (raw1.z >> 16) & 0xFFFF;
      jv[14] = raw1.w & 0xFFFF;  jv[15] = (raw1.w >> 16) & 0xFFFF;
      float dv[16];
#pragma unroll
      for (int u = 0; u < 16; ++u) {
        const bool ok = (e + u) < cnt;
        const int j = ok ? jv[u] : 0;        // mask BEFORE gather
        jv[u] = j;
        const float dd = ref_d2q(q2x, q2y, q2z, sq2, Cb[j]);  // 16 in flight
        dv[u] = ok ? dd : 3.4e38f;           // +inf pad: chain no-op
      }
#pragma unroll
      for (int u = 0; u < 16; ++u) {
        const float d = dv[u];
        const int j = jv[u];
        if (d < md[KK - 1]) {
          bool c0 = d < md[0];
#pragma unroll
          for (int t = KK - 1; t >= 1; --t) {
            bool cl = d < md[t];
            bool cp = d < md[t - 1];
            float nv = fmaxf(md[t - 1], fminf(md[t], d));
            mjr[t] = cl ? (cp ? mjr[t - 1] : j) : mjr[t];
            md[t] = nv;
          }
          mjr[0] = c0 ? j : mjr[0];
          md[0] = fminf(md[0], d);
        }
      }
    }
  } else {
    // exact full-scan insertion with index tracking (verbatim-proven)
    for (int j = 0; j < NP; ++j) {
      float d = ref_d2q(q2x, q2y, q2z, sq2, Cb[j]);
      if (d < md[KK - 1]) {
        bool c0 = d < md[0];
#pragma unroll
        for (int t = KK - 1; t >= 1; --t) {
          bool cl = d < md[t];
          bool cp = d < md[t - 1];
          float nv = fmaxf(md[t - 1], fminf(md[t], d));
          mjr[t] = cl ? (cp ? mjr[t - 1] : j) : mjr[t];
          md[t] = nv;
        }
        mjr[0] = c0 ? j : mjr[0];
        md[0] = fminf(md[0], d);
      }
    }
  }

  // cache the 16 selected points once (bitwise-identical values)
  float4 pts[KK];
#pragma unroll
  for (int s = 0; s < KK; ++s) pts[s] = Cb[mjr[s]];

  // ---- covariance + eigen tail (verbatim-verified arithmetic)
  float sx = 0.f, sy = 0.f, sz = 0.f;
#pragma unroll
  for (int s = 0; s < KK; ++s) {
    sx = __fadd_rn(sx, pts[s].x);
    sy = __fadd_rn(sy, pts[s].y);
    sz = __fadd_rn(sz, pts[s].z);
  }
  const float k1 = 1.0f / KK;   // exact power of two
  const float mx = sx * k1, my = sy * k1, mz = sz * k1;

  float cxx = 0.f, cxy = 0.f, cxz = 0.f, cyy = 0.f, cyz = 0.f, czz = 0.f;
#pragma unroll
  for (int s = 0; s < KK; ++s) {
    float dx = __fsub_rn(pts[s].x, mx);
    float dy = __fsub_rn(pts[s].y, my);
    float dz = __fsub_rn(pts[s].z, mz);
    cxx = __fadd_rn(cxx, __fmul_rn(dx, dx));
    cxy = __fadd_rn(cxy, __fmul_rn(dx, dy));
    cxz = __fadd_rn(cxz, __fmul_rn(dx, dz));
    cyy = __fadd_rn(cyy, __fmul_rn(dy, dy));
    cyz = __fadd_rn(cyz, __fmul_rn(dy, dz));
    czz = __fadd_rn(czz, __fmul_rn(dz, dz));
  }

  double a   = (double)__fmul_rn(cxx, k1), b = (double)__fmul_rn(cyy, k1);
  double c2  = (double)__fmul_rn(czz, k1);
  double dxy = (double)__fmul_rn(cxy, k1), exz = (double)__fmul_rn(cxz, k1);
  double fyz = (double)__fmul_rn(cyz, k1);
  double qm = (a + b + c2) / 3.0;
  double p1 = dxy * dxy + exz * exz + fyz * fyz;
  double aa = a - qm, bb = b - qm, cc = c2 - qm;
  double p2 = aa * aa + bb * bb + cc * cc + 2.0 * p1;
  double ratio;
  if (p2 <= 0.0) {
    ratio = 1.0;
  } else {
    double p  = sqrt(p2 / 6.0);
    double ip = 1.0 / p;
    double b00 = aa * ip, b11 = bb * ip, b22 = cc * ip;
    double b01 = dxy * ip, b02 = exz * ip, b12 = fyz * ip;
    double detB = b00 * (b11 * b22 - b12 * b12)
                - b01 * (b01 * b22 - b12 * b02)
                + b02 * (b01 * b12 - b11 * b02);
    double r = 0.5 * detB;
    r = fmin(1.0, fmax(-1.0, r));
    double phi = acos(r) / 3.0;
    double e0 = qm + 2.0 * p * cos(phi);                      // largest
    double e2 = qm + 2.0 * p * cos(phi + 2.0943951023931954); // smallest
    double e1 = 3.0 * qm - e0 - e2;                           // middle
    ratio = e0 / e1;
  }
  out[g] = (float)ratio;
}

// ---------------- fallback: verbatim single kernel (proven pass) ------------
__global__ __launch_bounds__(512, 4) void knn_eigen_fallback(
    const float4* __restrict__ cand, float* __restrict__ out) {
  __shared__ unsigned short s_j[8][QPB][18];

  const int tid   = threadIdx.x;
  const int lane  = tid & 63;
  const int w     = __builtin_amdgcn_readfirstlane(tid >> 6);
  const int batch = blockIdx.x >> 7;
  const int qbase = (blockIdx.x & 127) * QPB;
  const int FCH   = NP / 8;   // 1024

  const float4* __restrict__ Cb = cand + (size_t)batch * NP;

  const float4 q = Cb[qbase + lane];
  const float qx = q.x, qy = q.y, qz = q.z, sqq = q.w;

  float bd[KK];
#pragma unroll
  for (int t = 0; t < KK; ++t) bd[t] = 3.4e38f;

  const int j0 = w * FCH;
  for (int jj = 0; jj < FCH; jj += 8) {
    const float4* xp = Cb + (j0 + jj);
    float4 c[8];
#pragma unroll
    for (int u = 0; u < 8; ++u) c[u] = xp[u];
    float d[8];
#pragma unroll
    for (int u = 0; u < 8; ++u) d[u] = ref_d2q(qx, qy, qz, sqq, c[u]);
    topk_update(bd, d);
  }

  const float T = bd[KK - 1];
  int cnt = 0;
  for (int jj = 0; jj < FCH; jj += 8) {
    const float4* xp = Cb + (j0 + jj);
    float4 c[8];
#pragma unroll
    for (int u = 0; u < 8; ++u) c[u] = xp[u];
#pragma unroll
    for (int u = 0; u < 8; ++u) {
      float d = ref_d2q(qx, qy, qz, sqq, c[u]);
      if (d <= T && cnt < KK) {
        s_j[w][lane][cnt] = (unsigned short)(j0 + jj + u);
        cnt++;
      }
    }
  }
  __syncthreads();

  if (tid < QPB) {
    const float4 qq = Cb[qbase + tid];
    const float q2x = qq.x, q2y = qq.y, q2z = qq.z, sq2 = qq.w;
    float md[KK]; int mj[KK];
#pragma unroll
    for (int t = 0; t < KK; ++t) { md[t] = 3.4e38f; mj[t] = 0; }
    for (int cch = 0; cch < 8; ++cch) {
      const unsigned int* rowp = (const unsigned int*)&s_j[cch][tid][0];
#pragma unroll
      for (int sp = 0; sp < KK / 2; ++sp) {
        unsigned int pk = rowp[sp];
#pragma unroll
        for (int half = 0; half < 2; ++half) {
          int j = (half == 0) ? (int)(pk & 0xFFFFu) : (int)(pk >> 16);
          float d = ref_d2q(q2x, q2y, q2z, sq2, Cb[j]);
          if (d < md[KK - 1]) {
            bool c0 = d < md[0];
#pragma unroll
            for (int t = KK - 1; t >= 1; --t) {
              bool cl = d < md[t];
              bool cp = d < md[t - 1];
              float nv = fmaxf(md[t - 1], fminf(md[t], d));
              mj[t] = cl ? (cp ? mj[t - 1] : j) : mj[t];
              md[t] = nv;
            }
            mj[0] = c0 ? j : mj[0];
            md[0] = fminf(md[0], d);
          }
        }
      }
    }
    float sx = 0.f, sy = 0.f, sz = 0.f;
#pragma unroll
    for (int s = 0; s < KK; ++s) {
      float4 pp = Cb[mj[s]];
      sx = __fadd_rn(sx, pp.x);
      sy = __fadd_rn(sy, pp.y);
      sz = __fadd_rn(sz, pp.z);
    }
    const float k1 = 1.0f / KK;
    const float mx = sx * k1, my = sy * k1, mz = sz * k1;
    float cxx = 0.f, cxy = 0.f, cxz = 0.f, cyy = 0.f, cyz = 0.f, czz = 0.f;
#pragma unroll
    for (int s = 0; s < KK; ++s) {
      float4 pp = Cb[mj[s]];
      float dx = __fsub_rn(pp.x, mx);
      float dy = __fsub_rn(pp.y, my);
      float dz = __fsub_rn(pp.z, mz);
      cxx = __fadd_rn(cxx, __fmul_rn(dx, dx));
      cxy = __fadd_rn(cxy, __fmul_rn(dx, dy));
      cxz = __fadd_rn(cxz, __fmul_rn(dx, dz));
      cyy = __fadd_rn(cyy, __fmul_rn(dy, dy));
      cyz = __fadd_rn(cyz, __fmul_rn(dy, dz));
      czz = __fadd_rn(czz, __fmul_rn(dz, dz));
    }
    double a   = (double)__fmul_rn(cxx, k1), b = (double)__fmul_rn(cyy, k1);
    double c2  = (double)__fmul_rn(czz, k1);
    double dxy = (double)__fmul_rn(cxy, k1), exz = (double)__fmul_rn(cxz, k1);
    double fyz = (double)__fmul_rn(cyz, k1);
    double qm = (a + b + c2) / 3.0;
    double p1 = dxy * dxy + exz * exz + fyz * fyz;
    double aa = a - qm, bb = b - qm, cc = c2 - qm;
    double p2 = aa * aa + bb * bb + cc * cc + 2.0 * p1;
    double ratio;
    if (p2 <= 0.0) {
      ratio = 1.0;
    } else {
      double p  = sqrt(p2 / 6.0);
      double ip = 1.0 / p;
      double b00 = aa * ip, b11 = bb * ip, b22 = cc * ip;
      double b01 = dxy * ip, b02 = exz * ip, b12 = fyz * ip;
      double detB = b00 * (b11 * b22 - b12 * b12)
                  - b01 * (b01 * b22 - b12 * b02)
                  + b02 * (b01 * b12 - b11 * b02);
      double r = 0.5 * detB;
      r = fmin(1.0, fmax(-1.0, r));
      double phi = acos(r) / 3.0;
      double e0 = qm + 2.0 * p * cos(phi);
      double e2 = qm + 2.0 * p * cos(phi + 2.0943951023931954);
      double e1 = 3.0 * qm - e0 - e2;
      ratio = e0 / e1;
    }
    out[(size_t)batch * NP + qbase + tid] = (float)ratio;
  }
}

extern "C" void kernel_launch(void* const* d_in, const int* in_sizes, int n_in,
                              void* d_out, int out_size, void* d_ws, size_t ws_size,
                              hipStream_t stream) {
  const float* x = (const float*)d_in[0];
  float* out = (float*)d_out;
  float4* cand = (float4*)d_ws;                                   // 512 KB
  float* tauArr = (float*)((char*)d_ws + (size_t)NPTS * sizeof(float4)); // 128 KB
  unsigned short* rec =
      (unsigned short*)((char*)d_ws + (size_t)NPTS * sizeof(float4) +
                        (size_t)NPTS * sizeof(float));            // 15.5 MB
  const size_t need = (size_t)NPTS * sizeof(float4) +
                      (size_t)NPTS * sizeof(float) +
                      (size_t)NPTS * RECW * sizeof(unsigned short);
  // need = 16,908,288 B == proven budget

  prep_kernel<<<dim3(NPTS / 256), dim3(256), 0, stream>>>(x, cand);
  if (ws_size >= need) {
    tau_stage_kernel<<<dim3(512), dim3(512), 0, stream>>>(cand, tauArr);
    filter_kernel<<<dim3(512), dim3(512), 0, stream>>>(cand, tauArr, rec);
    select_eigen_kernel<<<dim3(NPTS / 64), dim3(64), 0, stream>>>(cand, rec, out);
  } else {
    knn_eigen_fallback<<<dim3(NPTS / QPB), dim3(512), 0, stream>>>(cand, out);
  }
}